// Round 6
// baseline (325.793 us; speedup 1.0000x reference)
//
#include <hip/hip_runtime.h>
#include <hip/hip_bf16.h>

typedef __attribute__((ext_vector_type(4))) float f32x4;
typedef __attribute__((ext_vector_type(8))) short short8;
typedef __attribute__((ext_vector_type(2))) unsigned int uint2v;

#define S_DIM 2048
#define D_DIM 64
#define KB 128
#define NHEADS 32
#define QTILES 32
#define NJT 16
#define TILE_USHORT (D_DIM * KB)     // 8192 ushorts = 16KB per (head, jtile)

static __device__ __forceinline__ unsigned short f2bf(float x) {
    union { __hip_bfloat16 h; unsigned short u; } c;
    c.h = __float2bfloat16(x);
    return c.u;
}
static __device__ __forceinline__ float bf2f(unsigned short u) {
    union { unsigned int i; float f; } c;
    c.i = ((unsigned int)u) << 16;
    return c.f;
}

// ---------------------------------------------------------------------------
// Prepass: V [head][j][d] fp32 -> blob[head][jt] = Vt[d][j_local] bf16,
// row-major 256B rows (main kernel reads it register-direct from L2).
// ---------------------------------------------------------------------------
__global__ __launch_bounds__(256)
void prep_v(const float* __restrict__ V, unsigned short* __restrict__ blob)
{
    const int b = blockIdx.x, head = b >> 4, jt = b & 15;
    const int t = threadIdx.x, d = t & 63, jg = t >> 6;
    const float* src = V + ((size_t)head * S_DIM + (size_t)jt * KB + jg * 32) * D_DIM + d;
    unsigned short* dst = blob + (size_t)(head * NJT + jt) * TILE_USHORT + d * KB + jg * 32;
    #pragma unroll
    for (int h = 0; h < 4; ++h) {
        short8 w;
        #pragma unroll
        for (int e = 0; e < 8; ++e)
            w[e] = (short)f2bf(src[(size_t)(h * 8 + e) * D_DIM]);
        *(short8*)(dst + h * 8) = w;
    }
}

// ---------------------------------------------------------------------------
// Main: flash softmax(L)·V. R5 structure (contiguous p-loads, per-wave LDS
// patch, register-direct V, no barriers) with the scratch spill removed:
// prefetch double-buffers are NAMED registers (pa0..7 / pb0..7), steps are
// macros — no arrays with taken addresses anywhere (rule #20).
// ---------------------------------------------------------------------------

// load the 8 f32x4 of tile TOFF (rows i0+2k+half, 16B at col 4*l5)
#define PLOAD(DST, TOFF) {                                                  \
    const float* s_ = lw + (size_t)(TOFF) * KB;                             \
    DST##0 = *(const f32x4*)(s_);                                           \
    DST##1 = *(const f32x4*)(s_ +  2 * (size_t)S_DIM);                      \
    DST##2 = *(const f32x4*)(s_ +  4 * (size_t)S_DIM);                      \
    DST##3 = *(const f32x4*)(s_ +  6 * (size_t)S_DIM);                      \
    DST##4 = *(const f32x4*)(s_ +  8 * (size_t)S_DIM);                      \
    DST##5 = *(const f32x4*)(s_ + 10 * (size_t)S_DIM);                      \
    DST##6 = *(const f32x4*)(s_ + 12 * (size_t)S_DIM);                      \
    DST##7 = *(const f32x4*)(s_ + 14 * (size_t)S_DIM);                      \
}

// exp + bf16 pack + swizzled 8B LDS write for one row-pair register
#define PK(SRCK, K) {                                                       \
    const int row_ = 2 * (K) + half;                                        \
    float e0_ = __expf(SRCK[0]), e1_ = __expf(SRCK[1]);                     \
    float e2_ = __expf(SRCK[2]), e3_ = __expf(SRCK[3]);                     \
    uint2v wv_;                                                             \
    wv_[0] = (unsigned)f2bf(e0_) | ((unsigned)f2bf(e1_) << 16);             \
    wv_[1] = (unsigned)f2bf(e2_) | ((unsigned)f2bf(e3_) << 16);             \
    *(uint2v*)(pw + row_ * 256 + ((l5 * 8) ^ ((row_ & 7) << 4))) = wv_;     \
}

#define STEP(CUR, NXT, T) {                                                 \
    if ((T) + 1 < NJT) PLOAD(NXT, (T) + 1);                                 \
    PK(CUR##0, 0) PK(CUR##1, 1) PK(CUR##2, 2) PK(CUR##3, 3)                 \
    PK(CUR##4, 4) PK(CUR##5, 5) PK(CUR##6, 6) PK(CUR##7, 7)                 \
    short8 afr[4];                                                          \
    _Pragma("unroll")                                                       \
    for (int c = 0; c < 4; ++c)                                             \
        afr[c] = *(const short8*)(pw + lr * 256 +                           \
                    (((c * 64) | (lg * 16)) ^ ((lr & 7) << 4)));            \
    _Pragma("unroll")                                                       \
    for (int c = 0; c < 4; ++c)                                             \
        _Pragma("unroll")                                                   \
        for (int e = 0; e < 8; ++e)                                         \
            lsum += bf2f((unsigned short)afr[c][e]);                        \
    const unsigned short* tile_ = hblob + (size_t)(T) * TILE_USHORT;        \
    _Pragma("unroll")                                                       \
    for (int c = 0; c < 4; ++c) {                                           \
        _Pragma("unroll")                                                   \
        for (int n = 0; n < 4; ++n) {                                       \
            short8 bfr = *(const short8*)(tile_ + (n * 16 + lr) * KB +      \
                                          c * 32 + lg * 8);                 \
            acc[n] = __builtin_amdgcn_mfma_f32_16x16x32_bf16(afr[c], bfr,   \
                                                             acc[n], 0, 0, 0); \
        }                                                                   \
    }                                                                       \
}

__global__ __launch_bounds__(256, 3)
void attn_main(const float* __restrict__ L,
               const unsigned short* __restrict__ blob,
               float* __restrict__ O)
{
    __shared__ __align__(16) unsigned char plds[4][4096];   // per-wave patches

    const int tid  = threadIdx.x;
    const int wave = tid >> 6;
    const int lane = tid & 63;
    const int lr   = lane & 15;     // A row / B col / D col
    const int lg   = lane >> 4;     // k-group
    const int half = lane >> 5;     // p-load: which of the 2 rows per instr
    const int l5   = lane & 31;     // p-load: 16B slot within the 512B chunk

    // XCD swizzle: 32 Q-tiles of a head share one XCD's L2
    const int bid  = blockIdx.x;
    const int xcd  = bid & 7;
    const int ixd  = bid >> 3;
    const int head = xcd * (NHEADS / 8) + (ixd >> 5);
    const int qt   = ixd & (QTILES - 1);
    const int i0   = qt * 64 + wave * 16;

    const float* lw = L + ((size_t)head * S_DIM + (size_t)(i0 + half)) * S_DIM + 4 * l5;
    const unsigned short* hblob = blob + (size_t)head * NJT * TILE_USHORT;
    unsigned char* pw = &plds[wave][0];

    f32x4 acc[4] = {};
    float lsum = 0.0f;

    f32x4 pa0, pa1, pa2, pa3, pa4, pa5, pa6, pa7;
    f32x4 pb0, pb1, pb2, pb3, pb4, pb5, pb6, pb7;

    PLOAD(pa, 0);

    #pragma unroll
    for (int tt = 0; tt < NJT / 2; ++tt) {
        STEP(pa, pb, 2 * tt)
        STEP(pb, pa, 2 * tt + 1)
    }

    // ---- epilogue: row sums (bf16-consistent), divide, store ----
    lsum += __shfl_xor(lsum, 16);
    lsum += __shfl_xor(lsum, 32);
    #pragma unroll
    for (int r = 0; r < 4; ++r) {
        const float inv = 1.0f / __shfl(lsum, lg * 4 + r);
        float* orow = O + ((size_t)head * S_DIM + (size_t)(i0 + lg * 4 + r)) * D_DIM;
        #pragma unroll
        for (int n = 0; n < 4; ++n)
            orow[n * 16 + lr] = acc[n][r] * inv;
    }
}

extern "C" void kernel_launch(void* const* d_in, const int* in_sizes, int n_in,
                              void* d_out, int out_size, void* d_ws, size_t ws_size,
                              hipStream_t stream) {
    const float* v = (const float*)d_in[0];
    const float* l = (const float*)d_in[1];
    float* out     = (float*)d_out;
    unsigned short* blob = (unsigned short*)d_ws;   // 8 MB used

    prep_v<<<dim3(NHEADS * NJT), dim3(256), 0, stream>>>(v, blob);
    attn_main<<<dim3(NHEADS * QTILES), dim3(256), 0, stream>>>(l, blob, out);
}

// Round 8
// 313.233 us; speedup vs baseline: 1.0401x; 1.0401x over previous
//
#include <hip/hip_runtime.h>
#include <hip/hip_bf16.h>

typedef __attribute__((ext_vector_type(4))) float f32x4;
typedef __attribute__((ext_vector_type(8))) short short8;
typedef __attribute__((ext_vector_type(2))) unsigned int uint2v;

#define S_DIM 2048
#define D_DIM 64
#define KB 128
#define NHEADS 32
#define QTILES 32
#define NJT 16
#define TILE_USHORT (D_DIM * KB)     // 8192 ushorts = 16KB per (head, jtile)

static __device__ __forceinline__ unsigned short f2bf(float x) {
    union { __hip_bfloat16 h; unsigned short u; } c;
    c.h = __float2bfloat16(x);
    return c.u;
}
static __device__ __forceinline__ float bf2f(unsigned short u) {
    union { unsigned int i; float f; } c;
    c.i = ((unsigned int)u) << 16;
    return c.f;
}

// ---------------------------------------------------------------------------
// Prepass: V [head][j][d] fp32 -> blob[head][jt] = Vt[d][j_local] bf16,
// row-major 256B rows (main kernel reads it register-direct from L2).
// ---------------------------------------------------------------------------
__global__ __launch_bounds__(256)
void prep_v(const float* __restrict__ V, unsigned short* __restrict__ blob)
{
    const int b = blockIdx.x, head = b >> 4, jt = b & 15;
    const int t = threadIdx.x, d = t & 63, jg = t >> 6;
    const float* src = V + ((size_t)head * S_DIM + (size_t)jt * KB + jg * 32) * D_DIM + d;
    unsigned short* dst = blob + (size_t)(head * NJT + jt) * TILE_USHORT + d * KB + jg * 32;
    #pragma unroll
    for (int h = 0; h < 4; ++h) {
        short8 w;
        #pragma unroll
        for (int e = 0; e < 8; ++e)
            w[e] = (short)f2bf(src[(size_t)(h * 8 + e) * D_DIM]);
        *(short8*)(dst + h * 8) = w;
    }
}

// ---------------------------------------------------------------------------
// Main: flash softmax(L)·V. Single variable vs R6: NO min-waves cap
// (__launch_bounds__(256) only) — R5/R6's (256,3) split the unified VGPR
// budget to 84 arch regs and spilled the prefetch buffers (WRITE_SIZE=230MB).
// lsum is computed from the afr readback (lane == row lr layout), which is
// the reduction R6 verified correct — R7's PK-phase lsum used the p-load
// layout (lane == 8 mixed rows) and broke the butterfly (absmax 2e-2).
// ---------------------------------------------------------------------------

// load the 8 f32x4 of tile TOFF (rows i0+2k+half, 16B at col 4*l5)
#define PLOAD(DST, TOFF) {                                                  \
    const float* s_ = lw + (size_t)(TOFF) * KB;                             \
    DST##0 = *(const f32x4*)(s_);                                           \
    DST##1 = *(const f32x4*)(s_ +  2 * (size_t)S_DIM);                      \
    DST##2 = *(const f32x4*)(s_ +  4 * (size_t)S_DIM);                      \
    DST##3 = *(const f32x4*)(s_ +  6 * (size_t)S_DIM);                      \
    DST##4 = *(const f32x4*)(s_ +  8 * (size_t)S_DIM);                      \
    DST##5 = *(const f32x4*)(s_ + 10 * (size_t)S_DIM);                      \
    DST##6 = *(const f32x4*)(s_ + 12 * (size_t)S_DIM);                      \
    DST##7 = *(const f32x4*)(s_ + 14 * (size_t)S_DIM);                      \
}

// exp + bf16 pack + swizzled 8B LDS write for one row-pair register
#define PK(SRCK, K) {                                                       \
    const int row_ = 2 * (K) + half;                                        \
    float e0_ = __expf(SRCK[0]), e1_ = __expf(SRCK[1]);                     \
    float e2_ = __expf(SRCK[2]), e3_ = __expf(SRCK[3]);                     \
    uint2v wv_;                                                             \
    wv_[0] = (unsigned)f2bf(e0_) | ((unsigned)f2bf(e1_) << 16);             \
    wv_[1] = (unsigned)f2bf(e2_) | ((unsigned)f2bf(e3_) << 16);             \
    *(uint2v*)(pw + row_ * 256 + ((l5 * 8) ^ ((row_ & 7) << 4))) = wv_;     \
}

#define STEP(CUR, NXT, T) {                                                 \
    if ((T) + 1 < NJT) PLOAD(NXT, (T) + 1);                                 \
    PK(CUR##0, 0) PK(CUR##1, 1) PK(CUR##2, 2) PK(CUR##3, 3)                 \
    PK(CUR##4, 4) PK(CUR##5, 5) PK(CUR##6, 6) PK(CUR##7, 7)                 \
    const unsigned short* tile_ = hblob + (size_t)(T) * TILE_USHORT;        \
    _Pragma("unroll")                                                       \
    for (int c = 0; c < 4; ++c) {                                           \
        short8 afr = *(const short8*)(pw + lr * 256 +                       \
                    (((c * 64) | (lg * 16)) ^ ((lr & 7) << 4)));            \
        _Pragma("unroll")                                                   \
        for (int e = 0; e < 8; ++e)                                         \
            lsum += bf2f((unsigned short)afr[e]);                           \
        _Pragma("unroll")                                                   \
        for (int n = 0; n < 4; ++n) {                                       \
            short8 bfr = *(const short8*)(tile_ + (n * 16 + lr) * KB +      \
                                          c * 32 + lg * 8);                 \
            acc[n] = __builtin_amdgcn_mfma_f32_16x16x32_bf16(afr, bfr,      \
                                                             acc[n], 0, 0, 0); \
        }                                                                   \
    }                                                                       \
}

__global__ __launch_bounds__(256)
void attn_main(const float* __restrict__ L,
               const unsigned short* __restrict__ blob,
               float* __restrict__ O)
{
    __shared__ __align__(16) unsigned char plds[4][4096];   // per-wave patches

    const int tid  = threadIdx.x;
    const int wave = tid >> 6;
    const int lane = tid & 63;
    const int lr   = lane & 15;     // A row / B col / D col
    const int lg   = lane >> 4;     // k-group
    const int half = lane >> 5;     // p-load: which of the 2 rows per instr
    const int l5   = lane & 31;     // p-load: 16B slot within the 512B chunk

    // XCD swizzle: 32 Q-tiles of a head share one XCD's L2
    const int bid  = blockIdx.x;
    const int xcd  = bid & 7;
    const int ixd  = bid >> 3;
    const int head = xcd * (NHEADS / 8) + (ixd >> 5);
    const int qt   = ixd & (QTILES - 1);
    const int i0   = qt * 64 + wave * 16;

    const float* lw = L + ((size_t)head * S_DIM + (size_t)(i0 + half)) * S_DIM + 4 * l5;
    const unsigned short* hblob = blob + (size_t)head * NJT * TILE_USHORT;
    unsigned char* pw = &plds[wave][0];

    f32x4 acc[4] = {};
    float lsum = 0.0f;

    f32x4 pa0, pa1, pa2, pa3, pa4, pa5, pa6, pa7;
    f32x4 pb0, pb1, pb2, pb3, pb4, pb5, pb6, pb7;

    PLOAD(pa, 0);

    #pragma unroll
    for (int tt = 0; tt < NJT / 2; ++tt) {
        STEP(pa, pb, 2 * tt)
        STEP(pb, pa, 2 * tt + 1)
    }

    // ---- epilogue: row sums (afr layout: lane lr == row), divide, store ----
    lsum += __shfl_xor(lsum, 16);
    lsum += __shfl_xor(lsum, 32);
    #pragma unroll
    for (int r = 0; r < 4; ++r) {
        const float inv = 1.0f / __shfl(lsum, lg * 4 + r);
        float* orow = O + ((size_t)head * S_DIM + (size_t)(i0 + lg * 4 + r)) * D_DIM;
        #pragma unroll
        for (int n = 0; n < 4; ++n)
            orow[n * 16 + lr] = acc[n][r] * inv;
    }
}

extern "C" void kernel_launch(void* const* d_in, const int* in_sizes, int n_in,
                              void* d_out, int out_size, void* d_ws, size_t ws_size,
                              hipStream_t stream) {
    const float* v = (const float*)d_in[0];
    const float* l = (const float*)d_in[1];
    float* out     = (float*)d_out;
    unsigned short* blob = (unsigned short*)d_ws;   // 8 MB used

    prep_v<<<dim3(NHEADS * NJT), dim3(256), 0, stream>>>(v, blob);
    attn_main<<<dim3(NHEADS * QTILES), dim3(256), 0, stream>>>(l, blob, out);
}

// Round 9
// 123.063 us; speedup vs baseline: 2.6474x; 2.5453x over previous
//
#include <hip/hip_runtime.h>
#include <hip/hip_bf16.h>

typedef __attribute__((ext_vector_type(4))) float f32x4;
typedef __attribute__((ext_vector_type(8))) short short8;

#define S_DIM 2048
#define D_DIM 64
#define KB 128
#define NHEADS 32
#define QTILES (S_DIM / 64)
#define NJT (S_DIM / KB)              // 16 j-tiles
#define TILE_BYTES (D_DIM * KB * 2)   // 16384 B per (head, jtile) blob

static __device__ __forceinline__ unsigned short f2bf(float x) {
    union { __hip_bfloat16 h; unsigned short u; } c;
    c.h = __float2bfloat16(x);
    return c.u;
}

// ---------------------------------------------------------------------------
// Prepass: V [head][j][d] fp32  ->  blob[head][jt] = 16KB LDS-image of
// Vt[d][j_local] bf16, rows of 256B, XOR-swizzled: byte ^= ((d&7)<<4).
// Main kernel stages these blobs with linear global_load_lds (identity copy).
// ---------------------------------------------------------------------------
__global__ __launch_bounds__(256)
void prep_v(const float* __restrict__ V, unsigned char* __restrict__ blob)
{
    const int b = blockIdx.x, head = b >> 4, jt = b & 15;
    const int t = threadIdx.x, d = t & 63, jg = t >> 6;   // jg: 32-j chunk
    const float* src = V + ((size_t)head * S_DIM + (size_t)jt * KB + jg * 32) * D_DIM + d;
    unsigned char* dst = blob + (size_t)(head * NJT + jt) * TILE_BYTES;
    #pragma unroll
    for (int h = 0; h < 4; ++h) {
        short8 w;
        #pragma unroll
        for (int e = 0; e < 8; ++e)
            w[e] = (short)f2bf(src[(size_t)(h * 8 + e) * D_DIM]);
        const int off = d * 256 + ((jg * 64 + h * 16) ^ ((d & 7) << 4));
        *(short8*)(dst + off) = w;
    }
}

// ---------------------------------------------------------------------------
// Main: flash-style softmax(L)·V (no max-subtraction; logits ~N(0,1)).
// V staged via global_load_lds into LDS (bfr reads live on LGKMCNT — a
// SEPARATE counter from the global p-loads' VMCNT, so the p prefetch
// overlaps the MFMA phase; R5-R8's register-direct global V put both
// streams on the in-order vmcnt queue and serialized every step on HBM
// latency — 2.8x slower). Counted vmcnt(8) + raw barrier keep the 8 HBM
// p-loads of tile t+1 in flight across the barrier.
// Per-CU delivery model: 4 blk/CU x (512KB logits + 256KB blob) = 3MB at
// ~25GB/s/CU share of 6.4TB/s => ~120us — this structure measures 122us.
// ---------------------------------------------------------------------------
__global__ __launch_bounds__(256, 4)
void attn_main(const float* __restrict__ L,
               const unsigned char* __restrict__ blob,
               float* __restrict__ O)
{
    __shared__ __align__(16) unsigned char vt[2][TILE_BYTES];   // 32 KB

    const int tid  = threadIdx.x;
    const int wave = tid >> 6;
    const int lane = tid & 63;
    const int lr   = lane & 15;     // A row / B col / D col
    const int lg   = lane >> 4;     // k-group

    // XCD swizzle: 32 Q-tiles of a head share one XCD's L2 (blob slice 256 KB)
    const int bid  = blockIdx.x;
    const int xcd  = bid & 7;
    const int ixd  = bid >> 3;
    const int head = xcd * (NHEADS / 8) + (ixd >> 5);
    const int qt   = ixd & (QTILES - 1);

    const int i0 = qt * 64 + wave * 16;
    const float* lrow = L + ((size_t)head * S_DIM + (size_t)(i0 + lr)) * S_DIM;
    const unsigned char* hblob = blob + (size_t)head * NJT * TILE_BYTES;

    f32x4 acc[4] = {};
    float lsum = 0.0f;
    float pv[32];

    // ---- prologue: stage vt tile 0, issue p tile 0 ----
    #pragma unroll
    for (int q = 0; q < 4; ++q)
        __builtin_amdgcn_global_load_lds(
            (const __attribute__((address_space(1))) void*)(hblob + q * 4096 + tid * 16),
            (__attribute__((address_space(3))) void*)(&vt[0][q * 4096 + tid * 16]),
            16, 0, 0);
    #pragma unroll
    for (int c = 0; c < 4; ++c) {
        f32x4 a = *(const f32x4*)(lrow + c * 32 + lg * 8);
        f32x4 b = *(const f32x4*)(lrow + c * 32 + lg * 8 + 4);
        pv[c*8+0]=a[0]; pv[c*8+1]=a[1]; pv[c*8+2]=a[2]; pv[c*8+3]=a[3];
        pv[c*8+4]=b[0]; pv[c*8+5]=b[1]; pv[c*8+6]=b[2]; pv[c*8+7]=b[3];
    }
    asm volatile("s_waitcnt vmcnt(8)" ::: "memory");   // glds(0) done; ploads in flight
    __builtin_amdgcn_s_barrier();

    for (int t = 0; t < NJT; ++t) {
        const int cur = t & 1;

        // issue next vt tile into the other buffer (fully read before the
        // barrier at the end of iter t-1)
        if (t + 1 < NJT) {
            const unsigned char* nsrc = hblob + (size_t)(t + 1) * TILE_BYTES;
            #pragma unroll
            for (int q = 0; q < 4; ++q)
                __builtin_amdgcn_global_load_lds(
                    (const __attribute__((address_space(1))) void*)(nsrc + q * 4096 + tid * 16),
                    (__attribute__((address_space(3))) void*)(&vt[cur ^ 1][q * 4096 + tid * 16]),
                    16, 0, 0);
        }

        // ---- softmax numerator: e = exp(x); lane-local running sum ----
        short8 afr[4];
        #pragma unroll
        for (int c = 0; c < 4; ++c) {
            #pragma unroll
            for (int e = 0; e < 8; ++e) {
                float ev = __expf(pv[c*8+e]);
                lsum += ev;
                afr[c][e] = (short)f2bf(ev);
            }
        }

        // ---- issue ploads(t+1): a full iteration of HBM-latency overlap ----
        if (t + 1 < NJT) {
            const float* s = lrow + (size_t)(t + 1) * KB;
            #pragma unroll
            for (int c = 0; c < 4; ++c) {
                f32x4 a = *(const f32x4*)(s + c * 32 + lg * 8);
                f32x4 b = *(const f32x4*)(s + c * 32 + lg * 8 + 4);
                pv[c*8+0]=a[0]; pv[c*8+1]=a[1]; pv[c*8+2]=a[2]; pv[c*8+3]=a[3];
                pv[c*8+4]=b[0]; pv[c*8+5]=b[1]; pv[c*8+6]=b[2]; pv[c*8+7]=b[3];
            }
        }

        // ---- MFMA: acc[n] += P(16x32) x V(32x16), swizzled B reads (LGKM) ----
        #pragma unroll
        for (int c = 0; c < 4; ++c) {
            #pragma unroll
            for (int n = 0; n < 4; ++n) {
                const int off = ((n * 16 + lr) << 8)
                              + (((c << 6) | (lg << 4)) ^ ((lr & 7) << 4));
                short8 bfr = *(const short8*)&vt[cur][off];
                acc[n] = __builtin_amdgcn_mfma_f32_16x16x32_bf16(afr[c], bfr, acc[n], 0, 0, 0);
            }
        }
        // ds_reads all register-consumed by MFMA above (compiler lgkm waits)

        if (t + 1 < NJT) {
            // retire the 4 glds(t+1) (L2-resident, covered by MFMA phase);
            // keep the 8 HBM ploads(t+1) outstanding across the barrier
            asm volatile("s_waitcnt vmcnt(8)" ::: "memory");
            __builtin_amdgcn_s_barrier();
        }
    }

    // ---- epilogue: row sums, divide, store ----
    lsum += __shfl_xor(lsum, 16);
    lsum += __shfl_xor(lsum, 32);
    #pragma unroll
    for (int r = 0; r < 4; ++r) {
        const float li  = __shfl(lsum, lg * 4 + r);
        const float inv = 1.0f / li;
        float* orow = O + ((size_t)head * S_DIM + (size_t)(i0 + lg * 4 + r)) * D_DIM;
        #pragma unroll
        for (int n = 0; n < 4; ++n)
            orow[n * 16 + lr] = acc[n][r] * inv;
    }
}

extern "C" void kernel_launch(void* const* d_in, const int* in_sizes, int n_in,
                              void* d_out, int out_size, void* d_ws, size_t ws_size,
                              hipStream_t stream) {
    const float* v = (const float*)d_in[0];
    const float* l = (const float*)d_in[1];
    float* out     = (float*)d_out;
    unsigned char* blob = (unsigned char*)d_ws;   // 8 MB used

    prep_v<<<dim3(NHEADS * NJT), dim3(256), 0, stream>>>(v, blob);
    attn_main<<<dim3(NHEADS * QTILES), dim3(256), 0, stream>>>(l, blob, out);
}